// Round 1
// baseline (317.754 us; speedup 1.0000x reference)
//
#include <hip/hip_runtime.h>

// ColBERT maxsim: out[b] = sum_q max_k ( mask[b,k] ? <D[b,k,:], Q[b/8,q,:]> : -9999 )
// B*NWAY = 1024 docs, DLEN=220 doc tokens, QLEN=32 query tokens, DIM=128.
//
// Strategy: 1 block (256 threads = 4 waves) per doc; lane-over-k (one doc-token
// row per lane). Each lane streams its D row via float4 global loads (lines fully
// consumed), Q operands are block-uniform -> scalar s_loads (constant cache),
// so the inner loop is nearly pure v_fma_f32. Epilogue: mask -> wave butterfly
// max per q -> LDS cross-wave max -> shuffle sum over q -> single store.

#define QLEN 32
#define DIM  128
#define DLEN 220

__global__ __launch_bounds__(256, 4)
void colbert_maxsim(const float* __restrict__ Q,
                    const float* __restrict__ D,
                    const int*   __restrict__ Dm,
                    float* __restrict__ out)
{
    const int b   = blockIdx.x;     // doc index [0, B*NWAY)
    const int tid = threadIdx.x;    // 0..255: lane-over-k
    const int qb  = b >> 3;         // query batch (nway = 8)

    const bool active = tid < DLEN;
    const int  krow   = active ? tid : 0;   // clamp inactive lanes in-bounds

    const float* __restrict__ qbase = Q + (size_t)qb * (QLEN * DIM);
    const float* __restrict__ drow  = D + ((size_t)b * DLEN + krow) * DIM;
    const int maskv = active ? Dm[(size_t)b * DLEN + tid] : 0;

    float dot[QLEN];
#pragma unroll
    for (int q = 0; q < QLEN; ++q) dot[q] = 0.f;

    // d-dim in chunks of 32 floats held in VGPRs; q-loop reuses each chunk 32x.
#pragma unroll
    for (int c = 0; c < DIM / 32; ++c) {
        float dv[32];
#pragma unroll
        for (int j = 0; j < 8; ++j) {
            const float4 t = *reinterpret_cast<const float4*>(drow + c * 32 + j * 4);
            dv[j * 4 + 0] = t.x; dv[j * 4 + 1] = t.y;
            dv[j * 4 + 2] = t.z; dv[j * 4 + 3] = t.w;
        }
#pragma unroll
        for (int q = 0; q < QLEN; ++q) {
            const float* __restrict__ qr = qbase + q * DIM + c * 32;  // uniform -> s_load
            float s0 = 0.f, s1 = 0.f, s2 = 0.f, s3 = 0.f;
#pragma unroll
            for (int j = 0; j < 32; j += 4) {
                s0 = fmaf(dv[j + 0], qr[j + 0], s0);
                s1 = fmaf(dv[j + 1], qr[j + 1], s1);
                s2 = fmaf(dv[j + 2], qr[j + 2], s2);
                s3 = fmaf(dv[j + 3], qr[j + 3], s3);
            }
            dot[q] += (s0 + s1) + (s2 + s3);
        }
    }

    // Mask: padded tokens (and lanes >= DLEN) contribute -9999, same as reference.
#pragma unroll
    for (int q = 0; q < QLEN; ++q)
        dot[q] = (maskv > 0) ? dot[q] : -9999.0f;

    // Per-q max across the wave's 64 doc-token rows (butterfly).
#pragma unroll
    for (int q = 0; q < QLEN; ++q) {
        float v = dot[q];
#pragma unroll
        for (int off = 32; off > 0; off >>= 1)
            v = fmaxf(v, __shfl_xor(v, off, 64));
        dot[q] = v;
    }

    // Cross-wave max via LDS, then sum over q, one store per doc.
    __shared__ float red[4][QLEN];
    const int wave = tid >> 6;
    const int lane = tid & 63;
    if (lane == 0) {
#pragma unroll
        for (int q = 0; q < QLEN; ++q) red[wave][q] = dot[q];
    }
    __syncthreads();

    if (tid < QLEN) {
        float m = fmaxf(fmaxf(red[0][tid], red[1][tid]),
                        fmaxf(red[2][tid], red[3][tid]));
#pragma unroll
        for (int off = 16; off > 0; off >>= 1)
            m += __shfl_xor(m, off, 64);
        if (tid == 0) out[b] = m;
    }
}

extern "C" void kernel_launch(void* const* d_in, const int* in_sizes, int n_in,
                              void* d_out, int out_size, void* d_ws, size_t ws_size,
                              hipStream_t stream)
{
    const float* Q  = (const float*)d_in[0];
    const float* D  = (const float*)d_in[1];
    const int*   Dm = (const int*)d_in[2];
    float* outp = (float*)d_out;
    // d_in[3] is nway (scalar, == 8): geometry is hard-coded to the reference.
    const int ndocs = out_size;   // B*NWAY = 1024
    colbert_maxsim<<<ndocs, 256, 0, stream>>>(Q, D, Dm, outp);
}

// Round 2
// 67.268 us; speedup vs baseline: 4.7237x; 4.7237x over previous
//
#include <hip/hip_runtime.h>

// ColBERT maxsim: out[b] = sum_q max_k ( mask[b,k] ? <D[b,k,:], Q[b/8,q,:]> : -9999 )
// B*NWAY = 1024 docs, DLEN=220 doc tokens, QLEN=32 query tokens, DIM=128.
//
// 1 block (256 threads = 4 waves) per doc; lane-over-k (one doc-token row per
// lane). D streamed as 16-float chunks held in four named float4s (NO indexed
// array -> no scratch). Q operands are block-uniform -> scalar s_loads.
// Inner loop: chained v_fma_f32 into dot[q]; ILP across the unrolled q loop.
//
// Round-1 lesson: __launch_bounds__(256,4) + dot[32]+dv[32] live -> compiler
// capped at 64 VGPR and spilled ~197 MB/dispatch to scratch (WRITE_SIZE).
// Fix: (256,2) cap + live set ~60 regs.

#define QLEN 32
#define DIM  128
#define DLEN 220

__global__ __launch_bounds__(256, 2)
void colbert_maxsim(const float* __restrict__ Q,
                    const float* __restrict__ D,
                    const int*   __restrict__ Dm,
                    float* __restrict__ out)
{
    const int b   = blockIdx.x;     // doc index [0, B*NWAY)
    const int tid = threadIdx.x;    // 0..255: lane-over-k
    const int qb  = b >> 3;         // query batch (nway = 8)

    const bool active = tid < DLEN;
    const int  krow   = active ? tid : 0;   // clamp inactive lanes in-bounds

    const float* __restrict__ qbase = Q + (size_t)qb * (QLEN * DIM);
    const float* __restrict__ drow  = D + ((size_t)b * DLEN + krow) * DIM;
    const int maskv = active ? Dm[(size_t)b * DLEN + tid] : 0;

    float dot[QLEN];
#pragma unroll
    for (int q = 0; q < QLEN; ++q) dot[q] = 0.f;

    // d-dim in chunks of 16 floats (one full 64B line per lane per chunk).
#pragma unroll
    for (int c = 0; c < DIM / 16; ++c) {
        const float4 t0 = *reinterpret_cast<const float4*>(drow + c * 16 + 0);
        const float4 t1 = *reinterpret_cast<const float4*>(drow + c * 16 + 4);
        const float4 t2 = *reinterpret_cast<const float4*>(drow + c * 16 + 8);
        const float4 t3 = *reinterpret_cast<const float4*>(drow + c * 16 + 12);
#pragma unroll
        for (int q = 0; q < QLEN; ++q) {
            const float* __restrict__ qr = qbase + q * DIM + c * 16; // uniform -> s_load
            float a = dot[q];
            a = fmaf(t0.x, qr[0],  a);
            a = fmaf(t0.y, qr[1],  a);
            a = fmaf(t0.z, qr[2],  a);
            a = fmaf(t0.w, qr[3],  a);
            a = fmaf(t1.x, qr[4],  a);
            a = fmaf(t1.y, qr[5],  a);
            a = fmaf(t1.z, qr[6],  a);
            a = fmaf(t1.w, qr[7],  a);
            a = fmaf(t2.x, qr[8],  a);
            a = fmaf(t2.y, qr[9],  a);
            a = fmaf(t2.z, qr[10], a);
            a = fmaf(t2.w, qr[11], a);
            a = fmaf(t3.x, qr[12], a);
            a = fmaf(t3.y, qr[13], a);
            a = fmaf(t3.z, qr[14], a);
            a = fmaf(t3.w, qr[15], a);
            dot[q] = a;
        }
    }

    // Mask: padded tokens (and lanes >= DLEN) contribute -9999, same as reference.
#pragma unroll
    for (int q = 0; q < QLEN; ++q)
        dot[q] = (maskv > 0) ? dot[q] : -9999.0f;

    // Per-q max across the wave's 64 doc-token rows (butterfly).
#pragma unroll
    for (int q = 0; q < QLEN; ++q) {
        float v = dot[q];
#pragma unroll
        for (int off = 32; off > 0; off >>= 1)
            v = fmaxf(v, __shfl_xor(v, off, 64));
        dot[q] = v;
    }

    // Cross-wave max via LDS, then sum over q, one store per doc.
    __shared__ float red[4][QLEN];
    const int wave = tid >> 6;
    const int lane = tid & 63;
    if (lane == 0) {
#pragma unroll
        for (int q = 0; q < QLEN; ++q) red[wave][q] = dot[q];
    }
    __syncthreads();

    if (tid < QLEN) {
        float m = fmaxf(fmaxf(red[0][tid], red[1][tid]),
                        fmaxf(red[2][tid], red[3][tid]));
#pragma unroll
        for (int off = 16; off > 0; off >>= 1)
            m += __shfl_xor(m, off, 64);
        if (tid == 0) out[b] = m;
    }
}

extern "C" void kernel_launch(void* const* d_in, const int* in_sizes, int n_in,
                              void* d_out, int out_size, void* d_ws, size_t ws_size,
                              hipStream_t stream)
{
    const float* Q  = (const float*)d_in[0];
    const float* D  = (const float*)d_in[1];
    const int*   Dm = (const int*)d_in[2];
    float* outp = (float*)d_out;
    // d_in[3] is nway (scalar, == 8): geometry is hard-coded to the reference.
    const int ndocs = out_size;   // B*NWAY = 1024
    colbert_maxsim<<<ndocs, 256, 0, stream>>>(Q, D, Dm, outp);
}

// Round 3
// 33.400 us; speedup vs baseline: 9.5136x; 2.0140x over previous
//
#include <hip/hip_runtime.h>

// ColBERT maxsim via MFMA: out[b] = sum_q max_k ( mask[b,k] ? <D[b,k,:], Q[b/8,q,:]> : -9999 )
// B*NWAY=1024 docs, DLEN=220, QLEN=32, DIM=128.
//
// Per doc: scores[220x32] = D(220x128) x Q^T(128x32) via mfma_f32_32x32x16_bf16.
// Inputs are f32; cast to bf16 in-register (abs err ~0.3 << threshold 20.8).
// Block = 448 threads (7 waves), one 32-token M-tile per wave, N=32 (one tile),
// K=128 in 8 steps. Both A (D rows) and B (Q rows) fragments are 8 contiguous
// f32 per lane -> direct global loads, no LDS staging. We use k = ks*16 + g*8 + j
// for BOTH operands; dot products are K-permutation invariant when A and B use
// the same mapping, so this is layout-safe.
// C/D layout (verified m74/m101): col(q) = lane&31, row(token) = (reg&3)+8*(reg>>2)+4*(lane>>5).
//
// Round-2 lesson: fp32 VALU path was issue+latency bound (VALUBusy 26%, HBM 10%).
// MFMA removes the 13.7us FMA-issue floor; kernel becomes HBM-bound (~18.4us floor).

#define QLEN   32
#define DIM    128
#define DLEN   220
#define NWAVES 7

typedef __attribute__((ext_vector_type(8)))  short bf16x8;
typedef __attribute__((ext_vector_type(16))) float f32x16;

__device__ __forceinline__ short f2bf(float f) {
    __bf16 h = (__bf16)f;                      // RNE hardware convert
    return __builtin_bit_cast(short, h);
}

__device__ __forceinline__ bf16x8 cvt8(const float4& a, const float4& b) {
    bf16x8 r;
    r[0] = f2bf(a.x); r[1] = f2bf(a.y); r[2] = f2bf(a.z); r[3] = f2bf(a.w);
    r[4] = f2bf(b.x); r[5] = f2bf(b.y); r[6] = f2bf(b.z); r[7] = f2bf(b.w);
    return r;
}

__global__ __launch_bounds__(448, 2)
void colbert_mfma(const float* __restrict__ Q,
                  const float* __restrict__ D,
                  const int*   __restrict__ Dm,
                  float* __restrict__ out)
{
    const int b    = blockIdx.x;        // doc
    const int tid  = threadIdx.x;
    const int wave = tid >> 6;          // 0..6 -> token tile
    const int lane = tid & 63;
    const int qb   = b >> 3;            // nway = 8

    const int col = lane & 31;          // A row (token-in-tile) / B col (q)
    const int g   = lane >> 5;          // k-group

    const int tbase = wave * 32;        // tokens [tbase, tbase+32)
    int arow = tbase + col;             // D row this lane loads
    if (arow > DLEN - 1) arow = DLEN - 1;   // clamp; garbage rows masked later

    const float* __restrict__ drow = D + ((size_t)b * DLEN + arow) * DIM;
    const float* __restrict__ qrow = Q + ((size_t)qb * QLEN + col) * DIM;

    // ---- bulk-issue all loads (Q: 16 float4, D: 16 float4 per lane) ----
    float4 qf[16];
#pragma unroll
    for (int ks = 0; ks < 8; ++ks) {
        const int koff = ks * 16 + g * 8;
        qf[2 * ks]     = *reinterpret_cast<const float4*>(qrow + koff);
        qf[2 * ks + 1] = *reinterpret_cast<const float4*>(qrow + koff + 4);
    }
    float4 af[16];
#pragma unroll
    for (int ks = 0; ks < 8; ++ks) {
        const int koff = ks * 16 + g * 8;
        af[2 * ks]     = *reinterpret_cast<const float4*>(drow + koff);
        af[2 * ks + 1] = *reinterpret_cast<const float4*>(drow + koff + 4);
    }

    // ---- convert + MFMA (K = 8 x 16) ----
    bf16x8 bq[8];
#pragma unroll
    for (int ks = 0; ks < 8; ++ks) bq[ks] = cvt8(qf[2 * ks], qf[2 * ks + 1]);

    f32x16 acc = {};
#pragma unroll
    for (int ks = 0; ks < 8; ++ks) {
        const bf16x8 a = cvt8(af[2 * ks], af[2 * ks + 1]);
        acc = __builtin_amdgcn_mfma_f32_32x32x16_bf16(a, bq[ks], acc, 0, 0, 0);
    }

    // ---- mask + max over this wave's 32 tokens ----
    // lane holds scores for q = col, tokens tbase + (reg&3) + 8*(reg>>2) + 4*g
    const int* __restrict__ dmb = Dm + (size_t)b * DLEN;
    float best = -9999.0f;
#pragma unroll
    for (int p = 0; p < 4; ++p) {
        const int r4  = tbase + p * 8 + g * 4;            // 4-aligned token base
        const int r4c = (r4 <= DLEN - 4) ? r4 : (DLEN - 4); // clamp (all-invalid case only)
        const int4 m4 = *reinterpret_cast<const int4*>(dmb + r4c);
        const float v0 = (r4 + 0 < DLEN && m4.x > 0) ? acc[4 * p + 0] : -9999.0f;
        const float v1 = (r4 + 1 < DLEN && m4.y > 0) ? acc[4 * p + 1] : -9999.0f;
        const float v2 = (r4 + 2 < DLEN && m4.z > 0) ? acc[4 * p + 2] : -9999.0f;
        const float v3 = (r4 + 3 < DLEN && m4.w > 0) ? acc[4 * p + 3] : -9999.0f;
        best = fmaxf(best, fmaxf(fmaxf(v0, v1), fmaxf(v2, v3)));
    }
    // combine the two k-groups' token halves (lanes l and l^32 share q)
    best = fmaxf(best, __shfl_xor(best, 32, 64));

    // ---- cross-wave max, then sum over q ----
    __shared__ float red[NWAVES][QLEN];
    if (lane < 32) red[wave][col] = best;
    __syncthreads();

    if (tid < QLEN) {
        float m = red[0][tid];
#pragma unroll
        for (int w = 1; w < NWAVES; ++w) m = fmaxf(m, red[w][tid]);
#pragma unroll
        for (int off = 16; off > 0; off >>= 1) m += __shfl_xor(m, off, 32);
        if (tid == 0) out[b] = m;
    }
}

extern "C" void kernel_launch(void* const* d_in, const int* in_sizes, int n_in,
                              void* d_out, int out_size, void* d_ws, size_t ws_size,
                              hipStream_t stream)
{
    const float* Q  = (const float*)d_in[0];
    const float* D  = (const float*)d_in[1];
    const int*   Dm = (const int*)d_in[2];
    float* outp = (float*)d_out;
    const int ndocs = out_size;   // B*NWAY = 1024
    colbert_mfma<<<ndocs, NWAVES * 64, 0, stream>>>(Q, D, Dm, outp);
}

// Round 4
// 29.295 us; speedup vs baseline: 10.8467x; 1.1401x over previous
//
#include <hip/hip_runtime.h>

// ColBERT maxsim via MFMA: out[b] = sum_q max_k ( mask[b,k] ? <D[b,k,:], Q[b/8,q,:]> : -9999 )
// B*NWAY=1024 docs, DLEN=220, QLEN=32, DIM=128.
//
// Round-3 lesson: 7-wave blocks + 32 bulk loads -> ~256 VGPR -> 1 block/CU ->
// 4 serial block-rounds per CU (latency-bound, 55% of achievable BW).
// Round-4 structure: 4-wave blocks, wave w does token tiles {w, w+4};
// K split in two 64-halves so D-staging is 8 float4 (32 VGPR) at a time;
// __launch_bounds__(256,4) caps at 128 VGPR -> all 4 blocks/CU resident.
// XCD swizzle keeps the 8 docs sharing a Q-tile on one XCD (Q HBM 16MB->2MB).
//
// MFMA mfma_f32_32x32x16_bf16, A=D-tile(32x128), B=Q^T. Both fragments are
// 8 contiguous f32 per lane -> direct global->reg, no LDS. Same k-mapping for
// A and B => layout-safe (dot product K-permutation invariant).
// C/D layout (m74/m101): col(q)=lane&31, row(token)=(reg&3)+8*(reg>>2)+4*(lane>>5).

#define QLEN   32
#define DIM    128
#define DLEN   220
#define NTILES 7
#define NWAVES 4

typedef __attribute__((ext_vector_type(8)))  short bf16x8;
typedef __attribute__((ext_vector_type(16))) float f32x16;

__device__ __forceinline__ short f2bf(float f) {
    __bf16 h = (__bf16)f;                      // RNE hardware convert
    return __builtin_bit_cast(short, h);
}

__device__ __forceinline__ bf16x8 cvt8(const float4& a, const float4& b) {
    bf16x8 r;
    r[0] = f2bf(a.x); r[1] = f2bf(a.y); r[2] = f2bf(a.z); r[3] = f2bf(a.w);
    r[4] = f2bf(b.x); r[5] = f2bf(b.y); r[6] = f2bf(b.z); r[7] = f2bf(b.w);
    return r;
}

__global__ __launch_bounds__(256, 4)
void colbert_mfma(const float* __restrict__ Q,
                  const float* __restrict__ D,
                  const int*   __restrict__ Dm,
                  float* __restrict__ out)
{
    // XCD swizzle (bijective: gridDim.x = 1024, %8 == 0): dispatch i -> XCD i%8,
    // so doc=(i%8)*cpx+i/8 puts consecutive docs (shared Q tile) on one XCD.
    const int cpx = gridDim.x >> 3;
    const int o   = blockIdx.x;
    const int b   = (o & 7) * cpx + (o >> 3);

    const int tid  = threadIdx.x;
    const int wave = tid >> 6;
    const int lane = tid & 63;
    const int qb   = b >> 3;            // nway = 8

    const int col = lane & 31;          // A row (token-in-tile) / B col (q)
    const int g   = lane >> 5;          // k-group

    // ---- Q fragment: load 16 float4, cvt to 8 bf16x8 (qf regs then freed) ----
    const float* __restrict__ qrow = Q + ((size_t)qb * QLEN + col) * DIM;
    float4 qf[16];
#pragma unroll
    for (int ks = 0; ks < 8; ++ks) {
        const int koff = ks * 16 + g * 8;
        qf[2 * ks]     = *reinterpret_cast<const float4*>(qrow + koff);
        qf[2 * ks + 1] = *reinterpret_cast<const float4*>(qrow + koff + 4);
    }
    bf16x8 bq[8];
#pragma unroll
    for (int ks = 0; ks < 8; ++ks) bq[ks] = cvt8(qf[2 * ks], qf[2 * ks + 1]);

    const int* __restrict__ dmb = Dm + (size_t)b * DLEN;
    float best = -9999.0f;

#pragma unroll
    for (int tt = 0; tt < 2; ++tt) {
        const int tile = wave + tt * NWAVES;     // wave-uniform
        if (tile < NTILES) {
            const int tbase = tile * 32;
            int arow = tbase + col;
            if (arow > DLEN - 1) arow = DLEN - 1;    // clamp; masked below
            const float* __restrict__ drow = D + ((size_t)b * DLEN + arow) * DIM;

            f32x16 acc = {};
#pragma unroll
            for (int h = 0; h < 2; ++h) {            // K in two 64-halves
                float4 af[8];
#pragma unroll
                for (int ksl = 0; ksl < 4; ++ksl) {
                    const int koff = (h * 4 + ksl) * 16 + g * 8;
                    af[2 * ksl]     = *reinterpret_cast<const float4*>(drow + koff);
                    af[2 * ksl + 1] = *reinterpret_cast<const float4*>(drow + koff + 4);
                }
#pragma unroll
                for (int ksl = 0; ksl < 4; ++ksl) {
                    const bf16x8 a = cvt8(af[2 * ksl], af[2 * ksl + 1]);
                    acc = __builtin_amdgcn_mfma_f32_32x32x16_bf16(a, bq[h * 4 + ksl],
                                                                  acc, 0, 0, 0);
                }
            }

            // mask + fold this tile into running per-(q=col) max
            // lane's acc reg r covers token tbase + (r&3) + 8*(r>>2) + 4*g
#pragma unroll
            for (int p = 0; p < 4; ++p) {
                const int r4  = tbase + p * 8 + g * 4;
                const int r4c = (r4 <= DLEN - 4) ? r4 : (DLEN - 4);
                const int4 m4 = *reinterpret_cast<const int4*>(dmb + r4c);
                const float v0 = (r4 + 0 < DLEN && m4.x > 0) ? acc[4 * p + 0] : -9999.0f;
                const float v1 = (r4 + 1 < DLEN && m4.y > 0) ? acc[4 * p + 1] : -9999.0f;
                const float v2 = (r4 + 2 < DLEN && m4.z > 0) ? acc[4 * p + 2] : -9999.0f;
                const float v3 = (r4 + 3 < DLEN && m4.w > 0) ? acc[4 * p + 3] : -9999.0f;
                best = fmaxf(best, fmaxf(fmaxf(v0, v1), fmaxf(v2, v3)));
            }
        }
    }

    // combine the two k-group token-halves (lanes l and l^32 share q=col)
    best = fmaxf(best, __shfl_xor(best, 32, 64));

    // ---- cross-wave max, then sum over q ----
    __shared__ float red[NWAVES][QLEN];
    if (lane < 32) red[wave][col] = best;
    __syncthreads();

    if (tid < QLEN) {
        float m = red[0][tid];
#pragma unroll
        for (int w = 1; w < NWAVES; ++w) m = fmaxf(m, red[w][tid]);
#pragma unroll
        for (int off = 16; off > 0; off >>= 1) m += __shfl_xor(m, off, 32);
        if (tid == 0) out[b] = m;
    }
}

extern "C" void kernel_launch(void* const* d_in, const int* in_sizes, int n_in,
                              void* d_out, int out_size, void* d_ws, size_t ws_size,
                              hipStream_t stream)
{
    const float* Q  = (const float*)d_in[0];
    const float* D  = (const float*)d_in[1];
    const int*   Dm = (const int*)d_in[2];
    float* outp = (float*)d_out;
    const int ndocs = out_size;   // B*NWAY = 1024 (divisible by 8 -> swizzle bijective)
    colbert_mfma<<<ndocs, NWAVES * 64, 0, stream>>>(Q, D, Dm, outp);
}

// Round 5
// 26.657 us; speedup vs baseline: 11.9200x; 1.0989x over previous
//
#include <hip/hip_runtime.h>

// ColBERT maxsim via MFMA + LDS staging.
// out[b] = sum_q max_k ( mask[b,k] ? <D[b,k,:], Q[b/8,q,:]> : -9999 )
// B*NWAY=1024 docs, DLEN=220, QLEN=32, DIM=128.
//
// Round-4 lesson: direct global->reg MFMA fragments are 16B/lane at 512B
// stride -> ~2 lanes per 128B line -> transaction-rate bound at ~4 TB/s.
// Round-5: coalesced global->reg (1024 contiguous B per wave-load, 4-deep),
// cvt f32->bf16, ds_write to a swizzled LDS tile; fragments come from
// ds_read_b128. LDS rows are 256B bf16: unswizzled ds_read_b128 would be a
// 32-way bank conflict -> byte ^= ((row&7)<<4) (m214 attn fix, +89% there).
// Doc staged in two chunks (128+92 rows, 32KB LDS) -> 4 blocks/CU.
//
// MFMA mfma_f32_32x32x16_bf16: A-frag lane(c=lane&31, g=lane>>5) holds
// row c, k=ks*16+g*8..+8 (same k-map for Q => layout-safe).
// C/D layout (m74/m101): col(q)=lane&31, row(token)=(reg&3)+8*(reg>>2)+4*g.

#define QLEN   32
#define DIM    128
#define DLEN   220
#define NWAVES 4
#define CROWS  128          // chunk0 rows; chunk1 = DLEN-CROWS = 92

typedef __attribute__((ext_vector_type(8)))  short bf16x8;
typedef __attribute__((ext_vector_type(16))) float f32x16;

__device__ __forceinline__ short f2bf(float f) {
    __bf16 h = (__bf16)f;                      // RNE hardware convert
    return __builtin_bit_cast(short, h);
}

__device__ __forceinline__ bf16x8 cvt8(const float4& a, const float4& b) {
    bf16x8 r;
    r[0] = f2bf(a.x); r[1] = f2bf(a.y); r[2] = f2bf(a.z); r[3] = f2bf(a.w);
    r[4] = f2bf(b.x); r[5] = f2bf(b.y); r[6] = f2bf(b.z); r[7] = f2bf(b.w);
    return r;
}

__global__ __launch_bounds__(256, 4)
void colbert_mfma(const float* __restrict__ Q,
                  const float* __restrict__ D,
                  const int*   __restrict__ Dm,
                  float* __restrict__ out)
{
    // XCD swizzle (bijective: gridDim.x = 1024 % 8 == 0): docs sharing a Q
    // tile land on one XCD's L2.
    const int cpx = gridDim.x >> 3;
    const int o   = blockIdx.x;
    const int b   = (o & 7) * cpx + (o >> 3);

    const int tid  = threadIdx.x;
    const int wave = tid >> 6;
    const int lane = tid & 63;
    const int qb   = b >> 3;            // nway = 8

    const int col = lane & 31;          // A row-in-tile / B col (q)
    const int g   = lane >> 5;          // k-group

    __shared__ __align__(16) short lds[CROWS * DIM];   // bf16, swizzled 256B rows
    __shared__ float red[NWAVES][QLEN];

    // ---- Q fragment: strided loads, but tiny volume (L2-resident) ----
    const float* __restrict__ qrow = Q + ((size_t)qb * QLEN + col) * DIM;
    bf16x8 bq[8];
#pragma unroll
    for (int ks = 0; ks < 8; ++ks) {
        const float4 x = *reinterpret_cast<const float4*>(qrow + ks * 16 + g * 8);
        const float4 y = *reinterpret_cast<const float4*>(qrow + ks * 16 + g * 8 + 4);
        bq[ks] = cvt8(x, y);
    }

    const int*   __restrict__ dmb   = Dm + (size_t)b * DLEN;
    const float* __restrict__ dbase = D + (size_t)b * DLEN * DIM;

    float best = -9999.0f;

#pragma unroll
    for (int ch = 0; ch < 2; ++ch) {
        const int rbase   = ch ? CROWS : 0;
        const int rows    = ch ? (DLEN - CROWS) : CROWS;   // 128 / 92
        const int nchunks = rows * 32;                     // 16B f32 chunks
        if (ch) __syncthreads();    // all reads of chunk0 done before overwrite

        // ---- stage: coalesced f32 loads (4-deep), cvt, swizzled bf16 write ----
        for (int t0 = 0; t0 < nchunks; t0 += 4 * 256) {
            float4 v[4];
            int    cc[4];
#pragma unroll
            for (int u = 0; u < 4; ++u) {
                int c = t0 + u * 256 + tid;
                cc[u] = c;
                const int cl = (c < nchunks) ? c : 0;      // clamp: always load
                const int row = cl >> 5, cir = cl & 31;
                v[u] = *reinterpret_cast<const float4*>(
                           dbase + (size_t)(rbase + row) * DIM + cir * 4);
            }
#pragma unroll
            for (int u = 0; u < 4; ++u) {
                if (cc[u] < nchunks) {
                    const int row = cc[u] >> 5, cir = cc[u] & 31;
                    short4 s;
                    s.x = f2bf(v[u].x); s.y = f2bf(v[u].y);
                    s.z = f2bf(v[u].z); s.w = f2bf(v[u].w);
                    const int byte = row * 256 + ((cir * 8) ^ ((row & 7) << 4));
                    *reinterpret_cast<short4*>(reinterpret_cast<char*>(lds) + byte) = s;
                }
            }
        }
        __syncthreads();

        // ---- compute: one 32-token tile per wave (chunk1: wave3 idles) ----
        const int ntiles = (rows + 31) >> 5;               // 4 / 3
        if (wave < ntiles) {
            const int tloc = wave * 32;
            int rloc = tloc + col;
            if (rloc > rows - 1) rloc = rows - 1;          // clamp; masked below

            f32x16 acc = {};
            const int rsw = (rloc & 7) << 4;
#pragma unroll
            for (int ks = 0; ks < 8; ++ks) {
                const int byte = rloc * 256 + ((ks * 32 + g * 16) ^ rsw);
                const bf16x8 a = *reinterpret_cast<const bf16x8*>(
                                     reinterpret_cast<const char*>(lds) + byte);
                acc = __builtin_amdgcn_mfma_f32_32x32x16_bf16(a, bq[ks], acc, 0, 0, 0);
            }

            // mask + fold into running per-(q=col) max.
            // lane's acc reg r covers token tbase + (r&3) + 8*(r>>2) + 4*g
            const int tbase = rbase + tloc;
#pragma unroll
            for (int p = 0; p < 4; ++p) {
                const int r4  = tbase + p * 8 + g * 4;
                const int r4c = (r4 <= DLEN - 4) ? r4 : (DLEN - 4);
                const int4 m4 = *reinterpret_cast<const int4*>(dmb + r4c);
                const float v0 = (r4 + 0 < DLEN && m4.x > 0) ? acc[4 * p + 0] : -9999.0f;
                const float v1 = (r4 + 1 < DLEN && m4.y > 0) ? acc[4 * p + 1] : -9999.0f;
                const float v2 = (r4 + 2 < DLEN && m4.z > 0) ? acc[4 * p + 2] : -9999.0f;
                const float v3 = (r4 + 3 < DLEN && m4.w > 0) ? acc[4 * p + 3] : -9999.0f;
                best = fmaxf(best, fmaxf(fmaxf(v0, v1), fmaxf(v2, v3)));
            }
        }
    }

    // combine the two k-group token-halves (lanes l and l^32 share q=col)
    best = fmaxf(best, __shfl_xor(best, 32, 64));

    // ---- cross-wave max, then sum over q ----
    if (lane < 32) red[wave][col] = best;
    __syncthreads();

    if (tid < QLEN) {
        float m = red[0][tid];
#pragma unroll
        for (int w = 1; w < NWAVES; ++w) m = fmaxf(m, red[w][tid]);
#pragma unroll
        for (int off = 16; off > 0; off >>= 1) m += __shfl_xor(m, off, 32);
        if (tid == 0) out[b] = m;
    }
}

extern "C" void kernel_launch(void* const* d_in, const int* in_sizes, int n_in,
                              void* d_out, int out_size, void* d_ws, size_t ws_size,
                              hipStream_t stream)
{
    const float* Q  = (const float*)d_in[0];
    const float* D  = (const float*)d_in[1];
    const int*   Dm = (const int*)d_in[2];
    float* outp = (float*)d_out;
    const int ndocs = out_size;   // B*NWAY = 1024
    colbert_mfma<<<ndocs, NWAVES * 64, 0, stream>>>(Q, D, Dm, outp);
}